// Round 1
// baseline (887.733 us; speedup 1.0000x reference)
//
#include <hip/hip_runtime.h>
#include <math.h>

#define B_    4
#define CIN_  128
#define COUT_ 128
#define H_    128
#define W_    128
#define HW_   (H_*W_)
#define KK_   9

// ---------------------------------------------------------------------------
// Kernel 1: 3x3 conv of feat with w_off (27 out channels), pad=1.
// Channels 0..17: raw offsets (y,x interleaved per tap). 18..26: sigmoid(mask).
// Output to ws as [B][27][H][W] f32.
// Block: 256 threads = 4 c-quarters x 64 pixels. Grid: 65536/64 = 1024.
// ---------------------------------------------------------------------------
__global__ __launch_bounds__(256) void offset_conv_kernel(
    const float* __restrict__ feat, const float* __restrict__ w_off,
    const float* __restrict__ b_off, float* __restrict__ offm)
{
    const int tid = threadIdx.x;
    const int q = tid >> 6;          // c-quarter 0..3 (wave-uniform)
    const int p = tid & 63;          // pixel within 64-chunk
    const int pix_base = blockIdx.x * 64;
    const int b = pix_base >> 14;    // /16384
    const int rem = pix_base & 16383;
    const int h = rem >> 7;
    const int w0 = rem & 127;        // 0 or 64
    const int w = w0 + p;

    __shared__ float s_part[4][64 * 27];

    float acc[27];
#pragma unroll
    for (int oc = 0; oc < 27; ++oc) acc[oc] = 0.f;

    const int c0 = q * 32;
    for (int c = c0; c < c0 + 32; ++c) {
        const float* fc = feat + ((size_t)(b * CIN_ + c)) * HW_;
        float f[9];
#pragma unroll
        for (int dy = 0; dy < 3; ++dy) {
            int y = h + dy - 1;
            bool vy = ((unsigned)y < (unsigned)H_);
#pragma unroll
            for (int dx = 0; dx < 3; ++dx) {
                int x = w + dx - 1;
                bool v = vy && ((unsigned)x < (unsigned)W_);
                f[dy * 3 + dx] = v ? fc[y * W_ + x] : 0.f;
            }
        }
        const float* wo = w_off + c * 9;   // + oc*1152 + t
#pragma unroll
        for (int t = 0; t < 9; ++t) {
            float ft = f[t];
#pragma unroll
            for (int oc = 0; oc < 27; ++oc)
                acc[oc] = fmaf(ft, wo[oc * 1152 + t], acc[oc]);
        }
    }
#pragma unroll
    for (int oc = 0; oc < 27; ++oc) s_part[q][p * 27 + oc] = acc[oc];
    __syncthreads();

    for (int i = tid; i < 64 * 27; i += 256) {
        int pp = i / 27;
        int oc = i - pp * 27;
        float v = s_part[0][i] + s_part[1][i] + s_part[2][i] + s_part[3][i]
                + b_off[oc];
        if (oc >= 18) v = 1.f / (1.f + __expf(-v));   // sigmoid for mask taps
        offm[((size_t)(b * 27 + oc)) * HW_ + h * W_ + w0 + pp] = v;
    }
}

// ---------------------------------------------------------------------------
// Kernel 2: modulated deformable conv.
// out[b,oc,h,w] = b_dc[oc] + sum_{c,k} V[c,k,h,w] * w_dc[oc,c,k]
//   V = mask * bilinear(inp[b,c], h+ky-1+offy, w+kx-1+offx)  (zero pad)
// Block per (b,h): 128 pixels x 128 out channels, 256 threads, 8x8 tile each.
// Bilinear metadata (4 clipped corner indices + 4 mask*valid weights) is
// computed once per block into registers; the c-loop stages V[9][128] and
// W[9][128] through LDS.
// ---------------------------------------------------------------------------
__global__ __launch_bounds__(256) void dcn_main_kernel(
    const float* __restrict__ inp, const float* __restrict__ offm,
    const float* __restrict__ w_dc, const float* __restrict__ b_dc,
    float* __restrict__ out)
{
    const int tid = threadIdx.x;
    const int b = blockIdx.x >> 7;
    const int h = blockIdx.x & 127;

    __shared__ __align__(16) float s_V[KK_ * 128];
    __shared__ __align__(16) float s_W[KK_ * 128];

    // ---- per-thread sampling metadata (items i = tid + j*256, i < 1152) ----
    int4   r_idx[5];
    float4 r_wgt[5];
    int woc[5], wk[5];
#pragma unroll
    for (int j = 0; j < 5; ++j) {
        int i = tid + j * 256;
        bool act = (j < 4) || (tid < 128);
        int ii = act ? i : 0;
        int k = ii >> 7;          // tap 0..8
        int p = ii & 127;         // pixel (w)
        int ky = k / 3, kx = k - ky * 3;
        const float* ob = offm + (size_t)b * 27 * HW_ + h * W_ + p;
        float offy = ob[(2 * k    ) * HW_];
        float offx = ob[(2 * k + 1) * HW_];
        float mask = ob[(18 + k   ) * HW_];
        float py = offy + (float)(h + ky - 1);
        float px = offx + (float)(p + kx - 1);
        float y0f = floorf(py), x0f = floorf(px);
        float ly = py - y0f, lx = px - x0f;
        int y0 = (int)y0f, x0 = (int)x0f;
        int y1 = y0 + 1, x1 = x0 + 1;
        bool vy0 = ((unsigned)y0 < (unsigned)H_);
        bool vy1 = ((unsigned)y1 < (unsigned)H_);
        bool vx0 = ((unsigned)x0 < (unsigned)W_);
        bool vx1 = ((unsigned)x1 < (unsigned)W_);
        int cy0 = min(max(y0, 0), H_ - 1), cy1 = min(max(y1, 0), H_ - 1);
        int cx0 = min(max(x0, 0), W_ - 1), cx1 = min(max(x1, 0), W_ - 1);
        r_idx[j] = make_int4(cy0 * W_ + cx0, cy0 * W_ + cx1,
                             cy1 * W_ + cx0, cy1 * W_ + cx1);
        float w00 = (1.f - ly) * (1.f - lx) * mask;
        float w01 = (1.f - ly) * lx * mask;
        float w10 = ly * (1.f - lx) * mask;
        float w11 = ly * lx * mask;
        if (!(vy0 && vx0)) w00 = 0.f;
        if (!(vy0 && vx1)) w01 = 0.f;
        if (!(vy1 && vx0)) w10 = 0.f;
        if (!(vy1 && vx1)) w11 = 0.f;
        r_wgt[j] = make_float4(w00, w01, w10, w11);
        woc[j] = ii / 9;
        wk[j]  = ii - (ii / 9) * 9;
    }

    const int tr = tid >> 4, tc = tid & 15;   // 16x16 thread grid
    float acc[8][8];
#pragma unroll
    for (int ii = 0; ii < 8; ++ii) {
        float bias = b_dc[tr * 8 + ii];
#pragma unroll
        for (int jj = 0; jj < 8; ++jj) acc[ii][jj] = bias;
    }

    const float* inp_b = inp + (size_t)b * CIN_ * HW_;
    for (int c = 0; c < CIN_; ++c) {
        __syncthreads();   // previous iteration's readers done
        const float* g = inp_b + c * HW_;
#pragma unroll
        for (int j = 0; j < 5; ++j) {
            if ((j < 4) || (tid < 128)) {
                int i = tid + j * 256;
                int4   id = r_idx[j];
                float4 wt = r_wgt[j];
                float v = g[id.x] * wt.x + g[id.y] * wt.y
                        + g[id.z] * wt.z + g[id.w] * wt.w;
                s_V[i] = v;
                s_W[wk[j] * 128 + woc[j]] =
                    w_dc[(woc[j] * CIN_ + c) * KK_ + wk[j]];
            }
        }
        __syncthreads();
#pragma unroll
        for (int k = 0; k < KK_; ++k) {
            const float4 v0 = *(const float4*)&s_V[k * 128 + tc * 8];
            const float4 v1 = *(const float4*)&s_V[k * 128 + tc * 8 + 4];
            const float4 w0 = *(const float4*)&s_W[k * 128 + tr * 8];
            const float4 w1 = *(const float4*)&s_W[k * 128 + tr * 8 + 4];
            float vv[8] = {v0.x, v0.y, v0.z, v0.w, v1.x, v1.y, v1.z, v1.w};
            float ww[8] = {w0.x, w0.y, w0.z, w0.w, w1.x, w1.y, w1.z, w1.w};
#pragma unroll
            for (int ii = 0; ii < 8; ++ii)
#pragma unroll
                for (int jj = 0; jj < 8; ++jj)
                    acc[ii][jj] = fmaf(ww[ii], vv[jj], acc[ii][jj]);
        }
    }

    float* ob = out + ((size_t)(b * COUT_ + tr * 8)) * HW_ + h * W_ + tc * 8;
#pragma unroll
    for (int ii = 0; ii < 8; ++ii) {
        *(float4*)(ob + (size_t)ii * HW_) =
            make_float4(acc[ii][0], acc[ii][1], acc[ii][2], acc[ii][3]);
        *(float4*)(ob + (size_t)ii * HW_ + 4) =
            make_float4(acc[ii][4], acc[ii][5], acc[ii][6], acc[ii][7]);
    }
}

extern "C" void kernel_launch(void* const* d_in, const int* in_sizes, int n_in,
                              void* d_out, int out_size, void* d_ws, size_t ws_size,
                              hipStream_t stream)
{
    const float* inp   = (const float*)d_in[0];
    const float* feat  = (const float*)d_in[1];
    const float* w_off = (const float*)d_in[2];
    const float* b_off = (const float*)d_in[3];
    const float* w_dc  = (const float*)d_in[4];
    const float* b_dc  = (const float*)d_in[5];
    float* out  = (float*)d_out;
    float* offm = (float*)d_ws;   // [4][27][128][128] f32 = 7.08 MB

    offset_conv_kernel<<<dim3(1024), dim3(256), 0, stream>>>(feat, w_off, b_off, offm);
    dcn_main_kernel<<<dim3(512), dim3(256), 0, stream>>>(inp, offm, w_dc, b_dc, out);
}

// Round 2
// 529.632 us; speedup vs baseline: 1.6761x; 1.6761x over previous
//
#include <hip/hip_runtime.h>
#include <math.h>

#define B_    4
#define CIN_  128
#define COUT_ 128
#define H_    128
#define W_    128
#define HW_   (H_*W_)
#define KK_   9

typedef __attribute__((ext_vector_type(8))) short short8;
typedef __attribute__((ext_vector_type(4))) float f32x4;

static __device__ __forceinline__ unsigned short f2bf(float f) {
    union { float f; unsigned u; } v; v.f = f;
    unsigned r = (v.u + 0x7fffu + ((v.u >> 16) & 1u)) >> 16;
    return (unsigned short)r;
}

// ---------------------------------------------------------------------------
// Kernel 1: 3x3 conv of feat with w_off (27 out channels), pad=1. UNCHANGED
// from round 1 (known-correct); counters next round once it's dominant.
// ---------------------------------------------------------------------------
__global__ __launch_bounds__(256) void offset_conv_kernel(
    const float* __restrict__ feat, const float* __restrict__ w_off,
    const float* __restrict__ b_off, float* __restrict__ offm)
{
    const int tid = threadIdx.x;
    const int q = tid >> 6;
    const int p = tid & 63;
    const int pix_base = blockIdx.x * 64;
    const int b = pix_base >> 14;
    const int rem = pix_base & 16383;
    const int h = rem >> 7;
    const int w0 = rem & 127;
    const int w = w0 + p;

    __shared__ float s_part[4][64 * 27];

    float acc[27];
#pragma unroll
    for (int oc = 0; oc < 27; ++oc) acc[oc] = 0.f;

    const int c0 = q * 32;
    for (int c = c0; c < c0 + 32; ++c) {
        const float* fc = feat + ((size_t)(b * CIN_ + c)) * HW_;
        float f[9];
#pragma unroll
        for (int dy = 0; dy < 3; ++dy) {
            int y = h + dy - 1;
            bool vy = ((unsigned)y < (unsigned)H_);
#pragma unroll
            for (int dx = 0; dx < 3; ++dx) {
                int x = w + dx - 1;
                bool v = vy && ((unsigned)x < (unsigned)W_);
                f[dy * 3 + dx] = v ? fc[y * W_ + x] : 0.f;
            }
        }
        const float* wo = w_off + c * 9;
#pragma unroll
        for (int t = 0; t < 9; ++t) {
            float ft = f[t];
#pragma unroll
            for (int oc = 0; oc < 27; ++oc)
                acc[oc] = fmaf(ft, wo[oc * 1152 + t], acc[oc]);
        }
    }
#pragma unroll
    for (int oc = 0; oc < 27; ++oc) s_part[q][p * 27 + oc] = acc[oc];
    __syncthreads();

    for (int i = tid; i < 64 * 27; i += 256) {
        int pp = i / 27;
        int oc = i - pp * 27;
        float v = s_part[0][i] + s_part[1][i] + s_part[2][i] + s_part[3][i]
                + b_off[oc];
        if (oc >= 18) v = 1.f / (1.f + __expf(-v));
        offm[((size_t)(b * 27 + oc)) * HW_ + h * W_ + w0 + pp] = v;
    }
}

// ---------------------------------------------------------------------------
// Kernel 1b: pre-swizzle w_dc into MFMA A-fragment order, bf16.
// K ordered tap-major: kk = k*128 + c. Chunk q (36 total): tap k=q>>2,
// c0=(q&3)*32. Layout: w_swz[q][ocb(8)][lane(64)][8 bf16], where
// oc = ocb*16 + (lane&15), c = c0 + (lane>>4)*8 + j  (A[m=lane&15][k=quad*8+j]).
// ---------------------------------------------------------------------------
__global__ __launch_bounds__(256) void wswz_kernel(
    const float* __restrict__ w_dc, unsigned short* __restrict__ w_swz)
{
    int idx = blockIdx.x * 256 + threadIdx.x;   // [0, 36*8*64)
    int q   = idx >> 9;
    int rem = idx & 511;
    int ocb = rem >> 6;
    int l   = rem & 63;
    int k   = q >> 2;
    int cb  = ((q & 3) << 5) + ((l >> 4) << 3);
    int oc  = (ocb << 4) + (l & 15);
    int4 pk;
    unsigned r[4];
#pragma unroll
    for (int j = 0; j < 4; ++j) {
        float f0 = w_dc[((size_t)(oc * CIN_ + cb + 2 * j    )) * KK_ + k];
        float f1 = w_dc[((size_t)(oc * CIN_ + cb + 2 * j + 1)) * KK_ + k];
        r[j] = (unsigned)f2bf(f0) | ((unsigned)f2bf(f1) << 16);
    }
    pk.x = r[0]; pk.y = r[1]; pk.z = r[2]; pk.w = r[3];
    *(int4*)&w_swz[(size_t)idx * 8] = pk;
}

// ---------------------------------------------------------------------------
// Kernel 2: modulated deformable conv as bf16 MFMA GEMM.
// Block = (b, h, half): 128 oc x 64 pixels, 4 waves in 2x2 grid (64oc x 32pix
// per wave, 4x2 tiles of 16x16). 36 K-chunks of 32 (fixed tap per chunk).
// Per chunk: build s_V[64 pix][40] bf16 via bilinear gathers (metadata from
// LDS, computed once), A-frags straight from global w_swz (L2-resident).
// ---------------------------------------------------------------------------
__global__ __launch_bounds__(256) void dcn_mfma_kernel(
    const float* __restrict__ inp, const float* __restrict__ offm,
    const unsigned short* __restrict__ w_swz, const float* __restrict__ b_dc,
    float* __restrict__ out)
{
    const int tid = threadIdx.x;
    const int bx  = blockIdx.x;
    const int b    = bx >> 8;
    const int h    = (bx & 255) >> 1;
    const int pw0  = (bx & 1) << 6;

    __shared__ int4   s_midx[576];        // [tap][pix]
    __shared__ float4 s_mwgt[576];
    __shared__ unsigned short s_V[64 * 40];  // [pix][kk_local], pad 32->40

    // ---- bilinear metadata: 9 taps x 64 pixels ----
#pragma unroll
    for (int j = 0; j < 3; ++j) {
        int i = tid + j * 256;
        if (i < 576) {
            int k = i >> 6, p = i & 63;
            int ky = k / 3, kx = k - ky * 3;
            int pw = pw0 + p;
            const float* ob = offm + (size_t)b * 27 * HW_ + h * W_ + pw;
            float offy = ob[(2 * k    ) * HW_];
            float offx = ob[(2 * k + 1) * HW_];
            float mask = ob[(18 + k   ) * HW_];
            float py = offy + (float)(h  + ky - 1);
            float px = offx + (float)(pw + kx - 1);
            float y0f = floorf(py), x0f = floorf(px);
            float ly = py - y0f, lx = px - x0f;
            int y0 = (int)y0f, x0 = (int)x0f;
            int y1 = y0 + 1, x1 = x0 + 1;
            bool vy0 = ((unsigned)y0 < (unsigned)H_);
            bool vy1 = ((unsigned)y1 < (unsigned)H_);
            bool vx0 = ((unsigned)x0 < (unsigned)W_);
            bool vx1 = ((unsigned)x1 < (unsigned)W_);
            int cy0 = min(max(y0, 0), H_ - 1), cy1 = min(max(y1, 0), H_ - 1);
            int cx0 = min(max(x0, 0), W_ - 1), cx1 = min(max(x1, 0), W_ - 1);
            int4 id = make_int4(cy0 * W_ + cx0, cy0 * W_ + cx1,
                                cy1 * W_ + cx0, cy1 * W_ + cx1);
            float w00 = (1.f - ly) * (1.f - lx) * mask;
            float w01 = (1.f - ly) * lx * mask;
            float w10 = ly * (1.f - lx) * mask;
            float w11 = ly * lx * mask;
            if (!(vy0 && vx0)) w00 = 0.f;
            if (!(vy0 && vx1)) w01 = 0.f;
            if (!(vy1 && vx0)) w10 = 0.f;
            if (!(vy1 && vx1)) w11 = 0.f;
            s_midx[i] = id;
            s_mwgt[i] = make_float4(w00, w01, w10, w11);
        }
    }

    const int lane = tid & 63;
    const int wave = tid >> 6;
    const int wr = wave >> 1;          // oc half: 0 -> oc 0..63, 1 -> 64..127
    const int wc = wave & 1;           // pix half: 0 -> 0..31, 1 -> 32..63
    const int p_build = tid & 63;      // build: pixel
    const int cgrp    = tid >> 6;      // build: 8-channel group

    f32x4 acc[4][2];
#pragma unroll
    for (int mt = 0; mt < 4; ++mt)
#pragma unroll
        for (int nt = 0; nt < 2; ++nt) acc[mt][nt] = (f32x4){0.f, 0.f, 0.f, 0.f};

    const float* gbase = inp + (size_t)b * CIN_ * HW_;
    const int kg = lane >> 4, pn = lane & 15;

    __syncthreads();   // metadata visible

    for (int q = 0; q < 36; ++q) {
        const int k  = q >> 2;
        const int c0 = (q & 3) << 5;

        // A-fragments from global (L2-resident swizzled weights)
        const short8* wp = (const short8*)w_swz + (size_t)(q * 8 + wr * 4) * 64 + lane;
        short8 af0 = wp[0];
        short8 af1 = wp[64];
        short8 af2 = wp[128];
        short8 af3 = wp[192];

        if (q) __syncthreads();        // previous chunk's B-frag reads done

        // ---- build V chunk: 32 channels x 64 pixels, bf16 ----
        int4   id = s_midx[(k << 6) + p_build];
        float4 wt = s_mwgt[(k << 6) + p_build];
        const float* g = gbase + (size_t)(c0 + (cgrp << 3)) * HW_;
        int4 pk;
        unsigned r[4];
#pragma unroll
        for (int i = 0; i < 4; ++i) {
            const float* g0 = g + (size_t)(2 * i) * HW_;
            const float* g1 = g0 + HW_;
            float v0 = g0[id.x] * wt.x + g0[id.y] * wt.y
                     + g0[id.z] * wt.z + g0[id.w] * wt.w;
            float v1 = g1[id.x] * wt.x + g1[id.y] * wt.y
                     + g1[id.z] * wt.z + g1[id.w] * wt.w;
            r[i] = (unsigned)f2bf(v0) | ((unsigned)f2bf(v1) << 16);
        }
        pk.x = r[0]; pk.y = r[1]; pk.z = r[2]; pk.w = r[3];
        *(int4*)&s_V[p_build * 40 + (cgrp << 3)] = pk;
        __syncthreads();

        // ---- B-fragments + MFMA ----
        short8 bf0 = *(const short8*)&s_V[(wc * 32      + pn) * 40 + kg * 8];
        short8 bf1 = *(const short8*)&s_V[(wc * 32 + 16 + pn) * 40 + kg * 8];

        acc[0][0] = __builtin_amdgcn_mfma_f32_16x16x32_bf16(af0, bf0, acc[0][0], 0, 0, 0);
        acc[0][1] = __builtin_amdgcn_mfma_f32_16x16x32_bf16(af0, bf1, acc[0][1], 0, 0, 0);
        acc[1][0] = __builtin_amdgcn_mfma_f32_16x16x32_bf16(af1, bf0, acc[1][0], 0, 0, 0);
        acc[1][1] = __builtin_amdgcn_mfma_f32_16x16x32_bf16(af1, bf1, acc[1][1], 0, 0, 0);
        acc[2][0] = __builtin_amdgcn_mfma_f32_16x16x32_bf16(af2, bf0, acc[2][0], 0, 0, 0);
        acc[2][1] = __builtin_amdgcn_mfma_f32_16x16x32_bf16(af2, bf1, acc[2][1], 0, 0, 0);
        acc[3][0] = __builtin_amdgcn_mfma_f32_16x16x32_bf16(af3, bf0, acc[3][0], 0, 0, 0);
        acc[3][1] = __builtin_amdgcn_mfma_f32_16x16x32_bf16(af3, bf1, acc[3][1], 0, 0, 0);
    }

    // ---- epilogue: C/D layout col=lane&15 (pix), row=(lane>>4)*4+i (oc) ----
    const int row0 = (lane >> 4) << 2;
    const int col  = lane & 15;
#pragma unroll
    for (int mt = 0; mt < 4; ++mt) {
#pragma unroll
        for (int nt = 0; nt < 2; ++nt) {
            int pw = pw0 + wc * 32 + nt * 16 + col;
#pragma unroll
            for (int i = 0; i < 4; ++i) {
                int oc = wr * 64 + mt * 16 + row0 + i;
                out[((size_t)(b * COUT_ + oc)) * HW_ + h * W_ + pw] =
                    acc[mt][nt][i] + b_dc[oc];
            }
        }
    }
}

extern "C" void kernel_launch(void* const* d_in, const int* in_sizes, int n_in,
                              void* d_out, int out_size, void* d_ws, size_t ws_size,
                              hipStream_t stream)
{
    const float* inp   = (const float*)d_in[0];
    const float* feat  = (const float*)d_in[1];
    const float* w_off = (const float*)d_in[2];
    const float* b_off = (const float*)d_in[3];
    const float* w_dc  = (const float*)d_in[4];
    const float* b_dc  = (const float*)d_in[5];
    float* out  = (float*)d_out;
    float* offm = (float*)d_ws;                       // [4][27][128][128] f32 = 7.08 MB
    unsigned short* w_swz = (unsigned short*)((char*)d_ws + 7077888);  // 288 KB bf16

    offset_conv_kernel<<<dim3(1024), dim3(256), 0, stream>>>(feat, w_off, b_off, offm);
    wswz_kernel<<<dim3(72), dim3(256), 0, stream>>>(w_dc, w_swz);
    dcn_mfma_kernel<<<dim3(1024), dim3(256), 0, stream>>>(inp, offm, w_swz, b_dc, out);
}

// Round 3
// 338.718 us; speedup vs baseline: 2.6209x; 1.5636x over previous
//
#include <hip/hip_runtime.h>
#include <math.h>

#define B_    4
#define CIN_  128
#define COUT_ 128
#define H_    128
#define W_    128
#define HW_   (H_*W_)
#define KK_   9

typedef __attribute__((ext_vector_type(8))) short short8;
typedef __attribute__((ext_vector_type(4))) float f32x4;

static __device__ __forceinline__ unsigned f2bf(float f) {
    union { float f; unsigned u; } v; v.f = f;
    return (v.u + 0x7fffu + ((v.u >> 16) & 1u)) >> 16;
}

// ---------------------------------------------------------------------------
// Prep A: swizzle w_dc into MFMA A-fragment order, bf16.
// w_swz[q][ocb(8)][lane(64)][8]: oc = ocb*16+(lane&15), c = (q&3)*32+(lane>>4)*8+j,
// tap k = q>>2.
// ---------------------------------------------------------------------------
__global__ __launch_bounds__(256) void wswz_kernel(
    const float* __restrict__ w_dc, unsigned short* __restrict__ w_swz)
{
    int idx = blockIdx.x * 256 + threadIdx.x;   // [0, 36*8*64)
    int q   = idx >> 9;
    int rem = idx & 511;
    int ocb = rem >> 6;
    int l   = rem & 63;
    int k   = q >> 2;
    int cb  = ((q & 3) << 5) + ((l >> 4) << 3);
    int oc  = (ocb << 4) + (l & 15);
    unsigned r[4];
#pragma unroll
    for (int j = 0; j < 4; ++j) {
        float f0 = w_dc[((size_t)(oc * CIN_ + cb + 2 * j    )) * KK_ + k];
        float f1 = w_dc[((size_t)(oc * CIN_ + cb + 2 * j + 1)) * KK_ + k];
        r[j] = f2bf(f0) | (f2bf(f1) << 16);
    }
    int4 pk = make_int4(r[0], r[1], r[2], r[3]);
    *(int4*)&w_swz[(size_t)idx * 8] = pk;
}

// ---------------------------------------------------------------------------
// Prep B: swizzle w_off into A-fragment order, bf16, oc padded 27->32 (zeros).
// woff_swz[q][mt(2)][lane(64)][8]: oc = mt*16+(lane&15), c = (q&3)*32+(lane>>4)*8+j,
// tap k = q>>2.
// ---------------------------------------------------------------------------
__global__ __launch_bounds__(256) void woffswz_kernel(
    const float* __restrict__ w_off, unsigned short* __restrict__ woff_swz)
{
    int idx = blockIdx.x * 256 + threadIdx.x;   // [0, 36*2*64)
    int q   = idx >> 7;
    int rem = idx & 127;
    int l   = rem & 63;
    int k   = q >> 2;
    int cb  = ((q & 3) << 5) + ((l >> 4) << 3);
    int oc  = ((rem >> 6) << 4) + (l & 15);
    unsigned r[4];
#pragma unroll
    for (int j = 0; j < 4; ++j) {
        float f0 = 0.f, f1 = 0.f;
        if (oc < 27) {
            f0 = w_off[((size_t)(oc * CIN_ + cb + 2 * j    )) * KK_ + k];
            f1 = w_off[((size_t)(oc * CIN_ + cb + 2 * j + 1)) * KK_ + k];
        }
        r[j] = f2bf(f0) | (f2bf(f1) << 16);
    }
    int4 pk = make_int4(r[0], r[1], r[2], r[3]);
    *(int4*)&woff_swz[(size_t)idx * 8] = pk;
}

// ---------------------------------------------------------------------------
// Kernel 1 (NEW): offset conv as bf16 MFMA GEMM.
// Block per (b,h): 512 blocks, 4 waves; wave w covers px w*32 (2 n-tiles),
// M = 2 tiles (oc 0..31, 27 real). 36 K-chunks of 32 channels, fixed tap per
// chunk: staging is a shifted coalesced row read of feat (no gather).
// Epilogue: +bias, sigmoid on oc>=18, write offm[b][27][H][W].
// ---------------------------------------------------------------------------
__global__ __launch_bounds__(256) void offset_mfma_kernel(
    const float* __restrict__ feat, const unsigned short* __restrict__ woff_swz,
    const float* __restrict__ b_off, float* __restrict__ offm)
{
    const int tid = threadIdx.x;
    const int b = blockIdx.x >> 7;
    const int h = blockIdx.x & 127;

    __shared__ unsigned short s_V[128 * 40];   // [pix][c_local], pad 32->40

    const int lane = tid & 63;
    const int wave = tid >> 6;
    const int px0  = wave << 5;
    const int kg = lane >> 4, pn = lane & 15;

    const int bp    = tid & 127;               // build: pixel
    const int chalf = (tid >> 7) << 4;         // build: channel base (0/16)

    f32x4 acc[2][2];
#pragma unroll
    for (int mt = 0; mt < 2; ++mt)
#pragma unroll
        for (int nt = 0; nt < 2; ++nt) acc[mt][nt] = (f32x4){0.f, 0.f, 0.f, 0.f};

    for (int q = 0; q < 36; ++q) {
        const int k  = q >> 2;
        const int c0 = (q & 3) << 5;
        const int ky = k / 3, kx = k - ky * 3;
        const int y  = h + ky - 1;
        const int x  = bp + kx - 1;

        const short8* wp = (const short8*)woff_swz + (size_t)(q * 2) * 64 + lane;
        short8 af0 = wp[0];
        short8 af1 = wp[64];

        if (q) __syncthreads();    // previous chunk's B-frag reads done

        unsigned r[8];
        if (((unsigned)y < (unsigned)H_) & ((unsigned)x < (unsigned)W_)) {
            const float* g = feat + ((size_t)(b * CIN_ + c0 + chalf)) * HW_
                           + y * W_ + x;
#pragma unroll
            for (int i = 0; i < 8; ++i) {
                float f0 = g[(size_t)(2 * i    ) * HW_];
                float f1 = g[(size_t)(2 * i + 1) * HW_];
                r[i] = f2bf(f0) | (f2bf(f1) << 16);
            }
        } else {
#pragma unroll
            for (int i = 0; i < 8; ++i) r[i] = 0;
        }
        *(int4*)&s_V[bp * 40 + chalf    ] = make_int4(r[0], r[1], r[2], r[3]);
        *(int4*)&s_V[bp * 40 + chalf + 8] = make_int4(r[4], r[5], r[6], r[7]);
        __syncthreads();

        short8 bf0 = *(const short8*)&s_V[(px0      + pn) * 40 + kg * 8];
        short8 bf1 = *(const short8*)&s_V[(px0 + 16 + pn) * 40 + kg * 8];

        acc[0][0] = __builtin_amdgcn_mfma_f32_16x16x32_bf16(af0, bf0, acc[0][0], 0, 0, 0);
        acc[0][1] = __builtin_amdgcn_mfma_f32_16x16x32_bf16(af0, bf1, acc[0][1], 0, 0, 0);
        acc[1][0] = __builtin_amdgcn_mfma_f32_16x16x32_bf16(af1, bf0, acc[1][0], 0, 0, 0);
        acc[1][1] = __builtin_amdgcn_mfma_f32_16x16x32_bf16(af1, bf1, acc[1][1], 0, 0, 0);
    }

    const int row0 = (lane >> 4) << 2;
    const int col  = lane & 15;
#pragma unroll
    for (int mt = 0; mt < 2; ++mt) {
#pragma unroll
        for (int nt = 0; nt < 2; ++nt) {
            int pw = px0 + nt * 16 + col;
#pragma unroll
            for (int i = 0; i < 4; ++i) {
                int oc = mt * 16 + row0 + i;
                if (oc < 27) {
                    float v = acc[mt][nt][i] + b_off[oc];
                    if (oc >= 18) v = 1.f / (1.f + __expf(-v));
                    offm[((size_t)(b * 27 + oc)) * HW_ + h * W_ + pw] = v;
                }
            }
        }
    }
}

// ---------------------------------------------------------------------------
// Kernel 2: modulated deformable conv as bf16 MFMA GEMM (unchanged from R2).
// ---------------------------------------------------------------------------
__global__ __launch_bounds__(256) void dcn_mfma_kernel(
    const float* __restrict__ inp, const float* __restrict__ offm,
    const unsigned short* __restrict__ w_swz, const float* __restrict__ b_dc,
    float* __restrict__ out)
{
    const int tid = threadIdx.x;
    const int bx  = blockIdx.x;
    const int b    = bx >> 8;
    const int h    = (bx & 255) >> 1;
    const int pw0  = (bx & 1) << 6;

    __shared__ int4   s_midx[576];
    __shared__ float4 s_mwgt[576];
    __shared__ unsigned short s_V[64 * 40];

#pragma unroll
    for (int j = 0; j < 3; ++j) {
        int i = tid + j * 256;
        if (i < 576) {
            int k = i >> 6, p = i & 63;
            int ky = k / 3, kx = k - ky * 3;
            int pw = pw0 + p;
            const float* ob = offm + (size_t)b * 27 * HW_ + h * W_ + pw;
            float offy = ob[(2 * k    ) * HW_];
            float offx = ob[(2 * k + 1) * HW_];
            float mask = ob[(18 + k   ) * HW_];
            float py = offy + (float)(h  + ky - 1);
            float px = offx + (float)(pw + kx - 1);
            float y0f = floorf(py), x0f = floorf(px);
            float ly = py - y0f, lx = px - x0f;
            int y0 = (int)y0f, x0 = (int)x0f;
            int y1 = y0 + 1, x1 = x0 + 1;
            bool vy0 = ((unsigned)y0 < (unsigned)H_);
            bool vy1 = ((unsigned)y1 < (unsigned)H_);
            bool vx0 = ((unsigned)x0 < (unsigned)W_);
            bool vx1 = ((unsigned)x1 < (unsigned)W_);
            int cy0 = min(max(y0, 0), H_ - 1), cy1 = min(max(y1, 0), H_ - 1);
            int cx0 = min(max(x0, 0), W_ - 1), cx1 = min(max(x1, 0), W_ - 1);
            int4 id = make_int4(cy0 * W_ + cx0, cy0 * W_ + cx1,
                                cy1 * W_ + cx0, cy1 * W_ + cx1);
            float w00 = (1.f - ly) * (1.f - lx) * mask;
            float w01 = (1.f - ly) * lx * mask;
            float w10 = ly * (1.f - lx) * mask;
            float w11 = ly * lx * mask;
            if (!(vy0 && vx0)) w00 = 0.f;
            if (!(vy0 && vx1)) w01 = 0.f;
            if (!(vy1 && vx0)) w10 = 0.f;
            if (!(vy1 && vx1)) w11 = 0.f;
            s_midx[i] = id;
            s_mwgt[i] = make_float4(w00, w01, w10, w11);
        }
    }

    const int lane = tid & 63;
    const int wave = tid >> 6;
    const int wr = wave >> 1;
    const int wc = wave & 1;
    const int p_build = tid & 63;
    const int cgrp    = tid >> 6;

    f32x4 acc[4][2];
#pragma unroll
    for (int mt = 0; mt < 4; ++mt)
#pragma unroll
        for (int nt = 0; nt < 2; ++nt) acc[mt][nt] = (f32x4){0.f, 0.f, 0.f, 0.f};

    const float* gbase = inp + (size_t)b * CIN_ * HW_;
    const int kg = lane >> 4, pn = lane & 15;

    __syncthreads();

    for (int q = 0; q < 36; ++q) {
        const int k  = q >> 2;
        const int c0 = (q & 3) << 5;

        const short8* wp = (const short8*)w_swz + (size_t)(q * 8 + wr * 4) * 64 + lane;
        short8 af0 = wp[0];
        short8 af1 = wp[64];
        short8 af2 = wp[128];
        short8 af3 = wp[192];

        if (q) __syncthreads();

        int4   id = s_midx[(k << 6) + p_build];
        float4 wt = s_mwgt[(k << 6) + p_build];
        const float* g = gbase + (size_t)(c0 + (cgrp << 3)) * HW_;
        unsigned r[4];
#pragma unroll
        for (int i = 0; i < 4; ++i) {
            const float* g0 = g + (size_t)(2 * i) * HW_;
            const float* g1 = g0 + HW_;
            float v0 = g0[id.x] * wt.x + g0[id.y] * wt.y
                     + g0[id.z] * wt.z + g0[id.w] * wt.w;
            float v1 = g1[id.x] * wt.x + g1[id.y] * wt.y
                     + g1[id.z] * wt.z + g1[id.w] * wt.w;
            r[i] = f2bf(v0) | (f2bf(v1) << 16);
        }
        *(int4*)&s_V[p_build * 40 + (cgrp << 3)] = make_int4(r[0], r[1], r[2], r[3]);
        __syncthreads();

        short8 bf0 = *(const short8*)&s_V[(wc * 32      + pn) * 40 + kg * 8];
        short8 bf1 = *(const short8*)&s_V[(wc * 32 + 16 + pn) * 40 + kg * 8];

        acc[0][0] = __builtin_amdgcn_mfma_f32_16x16x32_bf16(af0, bf0, acc[0][0], 0, 0, 0);
        acc[0][1] = __builtin_amdgcn_mfma_f32_16x16x32_bf16(af0, bf1, acc[0][1], 0, 0, 0);
        acc[1][0] = __builtin_amdgcn_mfma_f32_16x16x32_bf16(af1, bf0, acc[1][0], 0, 0, 0);
        acc[1][1] = __builtin_amdgcn_mfma_f32_16x16x32_bf16(af1, bf1, acc[1][1], 0, 0, 0);
        acc[2][0] = __builtin_amdgcn_mfma_f32_16x16x32_bf16(af2, bf0, acc[2][0], 0, 0, 0);
        acc[2][1] = __builtin_amdgcn_mfma_f32_16x16x32_bf16(af2, bf1, acc[2][1], 0, 0, 0);
        acc[3][0] = __builtin_amdgcn_mfma_f32_16x16x32_bf16(af3, bf0, acc[3][0], 0, 0, 0);
        acc[3][1] = __builtin_amdgcn_mfma_f32_16x16x32_bf16(af3, bf1, acc[3][1], 0, 0, 0);
    }

    const int row0 = (lane >> 4) << 2;
    const int col  = lane & 15;
#pragma unroll
    for (int mt = 0; mt < 4; ++mt) {
#pragma unroll
        for (int nt = 0; nt < 2; ++nt) {
            int pw = pw0 + wc * 32 + nt * 16 + col;
#pragma unroll
            for (int i = 0; i < 4; ++i) {
                int oc = wr * 64 + mt * 16 + row0 + i;
                out[((size_t)(b * COUT_ + oc)) * HW_ + h * W_ + pw] =
                    acc[mt][nt][i] + b_dc[oc];
            }
        }
    }
}

extern "C" void kernel_launch(void* const* d_in, const int* in_sizes, int n_in,
                              void* d_out, int out_size, void* d_ws, size_t ws_size,
                              hipStream_t stream)
{
    const float* inp   = (const float*)d_in[0];
    const float* feat  = (const float*)d_in[1];
    const float* w_off = (const float*)d_in[2];
    const float* b_off = (const float*)d_in[3];
    const float* w_dc  = (const float*)d_in[4];
    const float* b_dc  = (const float*)d_in[5];
    float* out  = (float*)d_out;
    float* offm = (float*)d_ws;                                            // 7.08 MB
    unsigned short* w_swz    = (unsigned short*)((char*)d_ws + 7077888);           // 288 KB
    unsigned short* woff_swz = (unsigned short*)((char*)d_ws + 7077888 + 294912);  // 72 KB

    woffswz_kernel<<<dim3(18), dim3(256), 0, stream>>>(w_off, woff_swz);
    wswz_kernel<<<dim3(72), dim3(256), 0, stream>>>(w_dc, w_swz);
    offset_mfma_kernel<<<dim3(512), dim3(256), 0, stream>>>(feat, woff_swz, b_off, offm);
    dcn_mfma_kernel<<<dim3(1024), dim3(256), 0, stream>>>(inp, offm, w_swz, b_dc, out);
}

// Round 4
// 326.144 us; speedup vs baseline: 2.7219x; 1.0386x over previous
//
#include <hip/hip_runtime.h>
#include <math.h>

#define B_    4
#define CIN_  128
#define COUT_ 128
#define H_    128
#define W_    128
#define HW_   (H_*W_)
#define KK_   9

typedef __attribute__((ext_vector_type(8))) short short8;
typedef __attribute__((ext_vector_type(4))) float f32x4;

static __device__ __forceinline__ unsigned f2bf(float f) {
    union { float f; unsigned u; } v; v.f = f;
    return (v.u + 0x7fffu + ((v.u >> 16) & 1u)) >> 16;
}

// K-chunk order (both GEMMs): q = cblock*9 + tap  (channel-OUTER, tap inner)
// so one 32-channel row footprint is reused by all 9 taps while L1/L2-hot.

// ---------------------------------------------------------------------------
// Prep A: swizzle w_dc into MFMA A-fragment order, bf16.
// w_swz[q][ocb(8)][lane(64)][8]: oc = ocb*16+(lane&15),
// c = (q/9)*32+(lane>>4)*8+j, tap k = q%9.
// ---------------------------------------------------------------------------
__global__ __launch_bounds__(256) void wswz_kernel(
    const float* __restrict__ w_dc, unsigned short* __restrict__ w_swz)
{
    int idx = blockIdx.x * 256 + threadIdx.x;   // [0, 36*8*64)
    int q   = idx >> 9;
    int rem = idx & 511;
    int ocb = rem >> 6;
    int l   = rem & 63;
    int cbq = q / 9;
    int k   = q - cbq * 9;
    int cb  = (cbq << 5) + ((l >> 4) << 3);
    int oc  = (ocb << 4) + (l & 15);
    unsigned r[4];
#pragma unroll
    for (int j = 0; j < 4; ++j) {
        float f0 = w_dc[((size_t)(oc * CIN_ + cb + 2 * j    )) * KK_ + k];
        float f1 = w_dc[((size_t)(oc * CIN_ + cb + 2 * j + 1)) * KK_ + k];
        r[j] = f2bf(f0) | (f2bf(f1) << 16);
    }
    int4 pk = make_int4(r[0], r[1], r[2], r[3]);
    *(int4*)&w_swz[(size_t)idx * 8] = pk;
}

// ---------------------------------------------------------------------------
// Prep B: swizzle w_off likewise, oc padded 27->32 (zeros).
// ---------------------------------------------------------------------------
__global__ __launch_bounds__(256) void woffswz_kernel(
    const float* __restrict__ w_off, unsigned short* __restrict__ woff_swz)
{
    int idx = blockIdx.x * 256 + threadIdx.x;   // [0, 36*2*64)
    int q   = idx >> 7;
    int rem = idx & 127;
    int l   = rem & 63;
    int cbq = q / 9;
    int k   = q - cbq * 9;
    int cb  = (cbq << 5) + ((l >> 4) << 3);
    int oc  = ((rem >> 6) << 4) + (l & 15);
    unsigned r[4];
#pragma unroll
    for (int j = 0; j < 4; ++j) {
        float f0 = 0.f, f1 = 0.f;
        if (oc < 27) {
            f0 = w_off[((size_t)(oc * CIN_ + cb + 2 * j    )) * KK_ + k];
            f1 = w_off[((size_t)(oc * CIN_ + cb + 2 * j + 1)) * KK_ + k];
        }
        r[j] = f2bf(f0) | (f2bf(f1) << 16);
    }
    int4 pk = make_int4(r[0], r[1], r[2], r[3]);
    *(int4*)&woff_swz[(size_t)idx * 8] = pk;
}

// ---------------------------------------------------------------------------
// Kernel 1: offset conv as bf16 MFMA GEMM (channel-outer chunks + XCD swizzle).
// ---------------------------------------------------------------------------
__global__ __launch_bounds__(256) void offset_mfma_kernel(
    const float* __restrict__ feat, const unsigned short* __restrict__ woff_swz,
    const float* __restrict__ b_off, float* __restrict__ offm)
{
    const int tid = threadIdx.x;
    // XCD swizzle: same XCD gets contiguous (b,h) range for L2 row reuse
    const int bx = blockIdx.x;
    const int lidx = ((bx & 7) << 6) | (bx >> 3);   // 512 blocks
    const int b = lidx >> 7;
    const int h = lidx & 127;

    __shared__ unsigned short s_V[128 * 40];   // [pix][c_local], pad 32->40

    const int lane = tid & 63;
    const int wave = tid >> 6;
    const int px0  = wave << 5;
    const int kg = lane >> 4, pn = lane & 15;

    const int bp    = tid & 127;               // build: pixel
    const int chalf = (tid >> 7) << 4;         // build: channel base (0/16)

    f32x4 acc[2][2];
#pragma unroll
    for (int mt = 0; mt < 2; ++mt)
#pragma unroll
        for (int nt = 0; nt < 2; ++nt) acc[mt][nt] = (f32x4){0.f, 0.f, 0.f, 0.f};

    for (int q = 0; q < 36; ++q) {
        const int cbq = q / 9;
        const int k   = q - cbq * 9;
        const int c0  = cbq << 5;
        const int ky = k / 3, kx = k - ky * 3;
        const int y  = h + ky - 1;
        const int x  = bp + kx - 1;

        const short8* wp = (const short8*)woff_swz + (size_t)(q * 2) * 64 + lane;
        short8 af0 = wp[0];
        short8 af1 = wp[64];

        if (q) __syncthreads();    // previous chunk's B-frag reads done

        unsigned r[8];
        if (((unsigned)y < (unsigned)H_) & ((unsigned)x < (unsigned)W_)) {
            const float* g = feat + ((size_t)(b * CIN_ + c0 + chalf)) * HW_
                           + y * W_ + x;
#pragma unroll
            for (int i = 0; i < 8; ++i) {
                float f0 = g[(size_t)(2 * i    ) * HW_];
                float f1 = g[(size_t)(2 * i + 1) * HW_];
                r[i] = f2bf(f0) | (f2bf(f1) << 16);
            }
        } else {
#pragma unroll
            for (int i = 0; i < 8; ++i) r[i] = 0;
        }
        *(int4*)&s_V[bp * 40 + chalf    ] = make_int4(r[0], r[1], r[2], r[3]);
        *(int4*)&s_V[bp * 40 + chalf + 8] = make_int4(r[4], r[5], r[6], r[7]);
        __syncthreads();

        short8 bf0 = *(const short8*)&s_V[(px0      + pn) * 40 + kg * 8];
        short8 bf1 = *(const short8*)&s_V[(px0 + 16 + pn) * 40 + kg * 8];

        acc[0][0] = __builtin_amdgcn_mfma_f32_16x16x32_bf16(af0, bf0, acc[0][0], 0, 0, 0);
        acc[0][1] = __builtin_amdgcn_mfma_f32_16x16x32_bf16(af0, bf1, acc[0][1], 0, 0, 0);
        acc[1][0] = __builtin_amdgcn_mfma_f32_16x16x32_bf16(af1, bf0, acc[1][0], 0, 0, 0);
        acc[1][1] = __builtin_amdgcn_mfma_f32_16x16x32_bf16(af1, bf1, acc[1][1], 0, 0, 0);
    }

    const int row0 = (lane >> 4) << 2;
    const int col  = lane & 15;
#pragma unroll
    for (int mt = 0; mt < 2; ++mt) {
#pragma unroll
        for (int nt = 0; nt < 2; ++nt) {
            int pw = px0 + nt * 16 + col;
#pragma unroll
            for (int i = 0; i < 4; ++i) {
                int oc = mt * 16 + row0 + i;
                if (oc < 27) {
                    float v = acc[mt][nt][i] + b_off[oc];
                    if (oc >= 18) v = 1.f / (1.f + __expf(-v));
                    offm[((size_t)(b * 27 + oc)) * HW_ + h * W_ + pw] = v;
                }
            }
        }
    }
}

// ---------------------------------------------------------------------------
// Kernel 2: modulated deformable conv as bf16 MFMA GEMM
// (channel-outer chunks + XCD swizzle).
// ---------------------------------------------------------------------------
__global__ __launch_bounds__(256) void dcn_mfma_kernel(
    const float* __restrict__ inp, const float* __restrict__ offm,
    const unsigned short* __restrict__ w_swz, const float* __restrict__ b_dc,
    float* __restrict__ out)
{
    const int tid = threadIdx.x;
    // XCD swizzle: 1024 blocks; same XCD covers contiguous (b,h,half) range
    const int bx = blockIdx.x;
    const int lidx = ((bx & 7) << 7) | (bx >> 3);
    const int b    = lidx >> 8;
    const int h    = (lidx & 255) >> 1;
    const int pw0  = (lidx & 1) << 6;

    __shared__ int4   s_midx[576];
    __shared__ float4 s_mwgt[576];
    __shared__ unsigned short s_V[64 * 40];

#pragma unroll
    for (int j = 0; j < 3; ++j) {
        int i = tid + j * 256;
        if (i < 576) {
            int k = i >> 6, p = i & 63;
            int ky = k / 3, kx = k - ky * 3;
            int pw = pw0 + p;
            const float* ob = offm + (size_t)b * 27 * HW_ + h * W_ + pw;
            float offy = ob[(2 * k    ) * HW_];
            float offx = ob[(2 * k + 1) * HW_];
            float mask = ob[(18 + k   ) * HW_];
            float py = offy + (float)(h  + ky - 1);
            float px = offx + (float)(pw + kx - 1);
            float y0f = floorf(py), x0f = floorf(px);
            float ly = py - y0f, lx = px - x0f;
            int y0 = (int)y0f, x0 = (int)x0f;
            int y1 = y0 + 1, x1 = x0 + 1;
            bool vy0 = ((unsigned)y0 < (unsigned)H_);
            bool vy1 = ((unsigned)y1 < (unsigned)H_);
            bool vx0 = ((unsigned)x0 < (unsigned)W_);
            bool vx1 = ((unsigned)x1 < (unsigned)W_);
            int cy0 = min(max(y0, 0), H_ - 1), cy1 = min(max(y1, 0), H_ - 1);
            int cx0 = min(max(x0, 0), W_ - 1), cx1 = min(max(x1, 0), W_ - 1);
            int4 id = make_int4(cy0 * W_ + cx0, cy0 * W_ + cx1,
                                cy1 * W_ + cx0, cy1 * W_ + cx1);
            float w00 = (1.f - ly) * (1.f - lx) * mask;
            float w01 = (1.f - ly) * lx * mask;
            float w10 = ly * (1.f - lx) * mask;
            float w11 = ly * lx * mask;
            if (!(vy0 && vx0)) w00 = 0.f;
            if (!(vy0 && vx1)) w01 = 0.f;
            if (!(vy1 && vx0)) w10 = 0.f;
            if (!(vy1 && vx1)) w11 = 0.f;
            s_midx[i] = id;
            s_mwgt[i] = make_float4(w00, w01, w10, w11);
        }
    }

    const int lane = tid & 63;
    const int wave = tid >> 6;
    const int wr = wave >> 1;
    const int wc = wave & 1;
    const int p_build = tid & 63;
    const int cgrp    = tid >> 6;

    f32x4 acc[4][2];
#pragma unroll
    for (int mt = 0; mt < 4; ++mt)
#pragma unroll
        for (int nt = 0; nt < 2; ++nt) acc[mt][nt] = (f32x4){0.f, 0.f, 0.f, 0.f};

    const float* gbase = inp + (size_t)b * CIN_ * HW_;
    const int kg = lane >> 4, pn = lane & 15;

    __syncthreads();

    for (int q = 0; q < 36; ++q) {
        const int cbq = q / 9;
        const int k   = q - cbq * 9;
        const int c0  = cbq << 5;

        const short8* wp = (const short8*)w_swz + (size_t)(q * 8 + wr * 4) * 64 + lane;
        short8 af0 = wp[0];
        short8 af1 = wp[64];
        short8 af2 = wp[128];
        short8 af3 = wp[192];

        if (q) __syncthreads();

        int4   id = s_midx[(k << 6) + p_build];
        float4 wt = s_mwgt[(k << 6) + p_build];
        const float* g = gbase + (size_t)(c0 + (cgrp << 3)) * HW_;
        unsigned r[4];
#pragma unroll
        for (int i = 0; i < 4; ++i) {
            const float* g0 = g + (size_t)(2 * i) * HW_;
            const float* g1 = g0 + HW_;
            float v0 = g0[id.x] * wt.x + g0[id.y] * wt.y
                     + g0[id.z] * wt.z + g0[id.w] * wt.w;
            float v1 = g1[id.x] * wt.x + g1[id.y] * wt.y
                     + g1[id.z] * wt.z + g1[id.w] * wt.w;
            r[i] = f2bf(v0) | (f2bf(v1) << 16);
        }
        *(int4*)&s_V[p_build * 40 + (cgrp << 3)] = make_int4(r[0], r[1], r[2], r[3]);
        __syncthreads();

        short8 bf0 = *(const short8*)&s_V[(wc * 32      + pn) * 40 + kg * 8];
        short8 bf1 = *(const short8*)&s_V[(wc * 32 + 16 + pn) * 40 + kg * 8];

        acc[0][0] = __builtin_amdgcn_mfma_f32_16x16x32_bf16(af0, bf0, acc[0][0], 0, 0, 0);
        acc[0][1] = __builtin_amdgcn_mfma_f32_16x16x32_bf16(af0, bf1, acc[0][1], 0, 0, 0);
        acc[1][0] = __builtin_amdgcn_mfma_f32_16x16x32_bf16(af1, bf0, acc[1][0], 0, 0, 0);
        acc[1][1] = __builtin_amdgcn_mfma_f32_16x16x32_bf16(af1, bf1, acc[1][1], 0, 0, 0);
        acc[2][0] = __builtin_amdgcn_mfma_f32_16x16x32_bf16(af2, bf0, acc[2][0], 0, 0, 0);
        acc[2][1] = __builtin_amdgcn_mfma_f32_16x16x32_bf16(af2, bf1, acc[2][1], 0, 0, 0);
        acc[3][0] = __builtin_amdgcn_mfma_f32_16x16x32_bf16(af3, bf0, acc[3][0], 0, 0, 0);
        acc[3][1] = __builtin_amdgcn_mfma_f32_16x16x32_bf16(af3, bf1, acc[3][1], 0, 0, 0);
    }

    const int row0 = (lane >> 4) << 2;
    const int col  = lane & 15;
#pragma unroll
    for (int mt = 0; mt < 4; ++mt) {
#pragma unroll
        for (int nt = 0; nt < 2; ++nt) {
            int pw = pw0 + wc * 32 + nt * 16 + col;
#pragma unroll
            for (int i = 0; i < 4; ++i) {
                int oc = wr * 64 + mt * 16 + row0 + i;
                out[((size_t)(b * COUT_ + oc)) * HW_ + h * W_ + pw] =
                    acc[mt][nt][i] + b_dc[oc];
            }
        }
    }
}

extern "C" void kernel_launch(void* const* d_in, const int* in_sizes, int n_in,
                              void* d_out, int out_size, void* d_ws, size_t ws_size,
                              hipStream_t stream)
{
    const float* inp   = (const float*)d_in[0];
    const float* feat  = (const float*)d_in[1];
    const float* w_off = (const float*)d_in[2];
    const float* b_off = (const float*)d_in[3];
    const float* w_dc  = (const float*)d_in[4];
    const float* b_dc  = (const float*)d_in[5];
    float* out  = (float*)d_out;
    float* offm = (float*)d_ws;                                            // 7.08 MB
    unsigned short* w_swz    = (unsigned short*)((char*)d_ws + 7077888);           // 288 KB
    unsigned short* woff_swz = (unsigned short*)((char*)d_ws + 7077888 + 294912);  // 72 KB

    woffswz_kernel<<<dim3(18), dim3(256), 0, stream>>>(w_off, woff_swz);
    wswz_kernel<<<dim3(72), dim3(256), 0, stream>>>(w_dc, w_swz);
    offset_mfma_kernel<<<dim3(512), dim3(256), 0, stream>>>(feat, woff_swz, b_off, offm);
    dcn_mfma_kernel<<<dim3(1024), dim3(256), 0, stream>>>(inp, offm, w_swz, b_dc, out);
}

// Round 5
// 286.957 us; speedup vs baseline: 3.0936x; 1.1366x over previous
//
#include <hip/hip_runtime.h>
#include <math.h>

#define B_    4
#define CIN_  128
#define COUT_ 128
#define H_    128
#define W_    128
#define HW_   (H_*W_)
#define KK_   9

typedef __attribute__((ext_vector_type(8))) short short8;
typedef __attribute__((ext_vector_type(4))) float f32x4;
typedef float f2v __attribute__((ext_vector_type(2), aligned(4)));  // 4B-aligned pair load

static __device__ __forceinline__ unsigned f2bf(float f) {
    union { float f; unsigned u; } v; v.f = f;
    return (v.u + 0x7fffu + ((v.u >> 16) & 1u)) >> 16;
}

// K-chunk order (both GEMMs): q = cblock*9 + tap (channel-outer, tap inner).

// ---------------------------------------------------------------------------
// Prep A: swizzle w_dc into MFMA A-fragment order, bf16 (unchanged).
// ---------------------------------------------------------------------------
__global__ __launch_bounds__(256) void wswz_kernel(
    const float* __restrict__ w_dc, unsigned short* __restrict__ w_swz)
{
    int idx = blockIdx.x * 256 + threadIdx.x;   // [0, 36*8*64)
    int q   = idx >> 9;
    int rem = idx & 511;
    int ocb = rem >> 6;
    int l   = rem & 63;
    int cbq = q / 9;
    int k   = q - cbq * 9;
    int cb  = (cbq << 5) + ((l >> 4) << 3);
    int oc  = (ocb << 4) + (l & 15);
    unsigned r[4];
#pragma unroll
    for (int j = 0; j < 4; ++j) {
        float f0 = w_dc[((size_t)(oc * CIN_ + cb + 2 * j    )) * KK_ + k];
        float f1 = w_dc[((size_t)(oc * CIN_ + cb + 2 * j + 1)) * KK_ + k];
        r[j] = f2bf(f0) | (f2bf(f1) << 16);
    }
    *(int4*)&w_swz[(size_t)idx * 8] = make_int4(r[0], r[1], r[2], r[3]);
}

// ---------------------------------------------------------------------------
// Prep B: swizzle w_off likewise, oc padded 27->32 (unchanged).
// ---------------------------------------------------------------------------
__global__ __launch_bounds__(256) void woffswz_kernel(
    const float* __restrict__ w_off, unsigned short* __restrict__ woff_swz)
{
    int idx = blockIdx.x * 256 + threadIdx.x;   // [0, 36*2*64)
    int q   = idx >> 7;
    int rem = idx & 127;
    int l   = rem & 63;
    int cbq = q / 9;
    int k   = q - cbq * 9;
    int cb  = (cbq << 5) + ((l >> 4) << 3);
    int oc  = ((rem >> 6) << 4) + (l & 15);
    unsigned r[4];
#pragma unroll
    for (int j = 0; j < 4; ++j) {
        float f0 = 0.f, f1 = 0.f;
        if (oc < 27) {
            f0 = w_off[((size_t)(oc * CIN_ + cb + 2 * j    )) * KK_ + k];
            f1 = w_off[((size_t)(oc * CIN_ + cb + 2 * j + 1)) * KK_ + k];
        }
        r[j] = f2bf(f0) | (f2bf(f1) << 16);
    }
    *(int4*)&woff_swz[(size_t)idx * 8] = make_int4(r[0], r[1], r[2], r[3]);
}

// ---------------------------------------------------------------------------
// Kernel 1: offset conv, bf16 MFMA GEMM. 64-px blocks (grid 1024, 4/CU),
// register-pipelined staging loads (issue q+1 between barriers of q).
// Block tile: 32 oc (27 real) x 64 px; wave w -> px w*16, 2 m-tiles.
// ---------------------------------------------------------------------------
__global__ __launch_bounds__(256) void offset_mfma_kernel(
    const float* __restrict__ feat, const unsigned short* __restrict__ woff_swz,
    const float* __restrict__ b_off, float* __restrict__ offm)
{
    const int tid = threadIdx.x;
    const int bx = blockIdx.x;
    const int lidx = ((bx & 7) << 7) | (bx >> 3);   // XCD swizzle, 1024 blocks
    const int b  = lidx >> 8;
    const int h  = (lidx & 255) >> 1;
    const int w0 = (lidx & 1) << 6;

    __shared__ unsigned short s_V[64 * 40];   // [pix][c_local 0..31], pad->40

    const int lane = tid & 63;
    const int wave = tid >> 6;
    const int kg = lane >> 4, pn = lane & 15;

    const int bp    = tid & 63;            // build pixel
    const int cgrp8 = (tid >> 6) << 3;     // build channel base (0,8,16,24)

    const float* fbase = feat + (size_t)b * CIN_ * HW_;

    f32x4 acc[2];
    acc[0] = (f32x4){0.f, 0.f, 0.f, 0.f};
    acc[1] = (f32x4){0.f, 0.f, 0.f, 0.f};

    float pf[8];

    // issue staging loads for chunk qq into pf
    auto issue = [&](int qq, float* p) {
        int cbq = qq / 9;
        int k   = qq - cbq * 9;
        int ky = k / 3, kx = k - ky * 3;
        int y = h + ky - 1;
        int x = w0 + bp + kx - 1;
        bool v = ((unsigned)y < (unsigned)H_) & ((unsigned)x < (unsigned)W_);
        const float* g = fbase + (size_t)((cbq << 5) + cgrp8) * HW_ + y * W_ + x;
#pragma unroll
        for (int i = 0; i < 8; ++i) p[i] = v ? g[(size_t)i * HW_] : 0.f;
    };

    issue(0, pf);

    for (int q = 0; q < 36; ++q) {
        // consume prefetched values -> bf16 pack
        unsigned r[4];
#pragma unroll
        for (int i = 0; i < 4; ++i)
            r[i] = f2bf(pf[2 * i]) | (f2bf(pf[2 * i + 1]) << 16);

        // A-fragments (L2-hot)
        const short8* wp = (const short8*)woff_swz + (size_t)(q * 2) * 64 + lane;
        short8 af0 = wp[0];
        short8 af1 = wp[64];

        if (q) __syncthreads();            // prior chunk's B reads done
        *(int4*)&s_V[bp * 40 + cgrp8] = make_int4(r[0], r[1], r[2], r[3]);

        int qn = (q + 1 < 36) ? q + 1 : 35;
        issue(qn, pf);                     // register loads cross the barrier

        __syncthreads();

        short8 bf = *(const short8*)&s_V[(wave * 16 + pn) * 40 + kg * 8];
        acc[0] = __builtin_amdgcn_mfma_f32_16x16x32_bf16(af0, bf, acc[0], 0, 0, 0);
        acc[1] = __builtin_amdgcn_mfma_f32_16x16x32_bf16(af1, bf, acc[1], 0, 0, 0);
    }

    const int row0 = (lane >> 4) << 2;
    const int col  = lane & 15;
    const int pw   = w0 + wave * 16 + col;
#pragma unroll
    for (int mt = 0; mt < 2; ++mt) {
#pragma unroll
        for (int i = 0; i < 4; ++i) {
            int oc = mt * 16 + row0 + i;
            if (oc < 27) {
                float v = acc[mt][i] + b_off[oc];
                if (oc >= 18) v = 1.f / (1.f + __expf(-v));
                offm[((size_t)(b * 27 + oc)) * HW_ + h * W_ + pw] = v;
            }
        }
    }
}

// ---------------------------------------------------------------------------
// Kernel 2: modulated deformable conv, bf16 MFMA GEMM. 32-px blocks
// (grid 2048, 8/CU), corner-paired dwordx2 gathers with folded pair weights,
// register-pipelined (gathers for q+1 issued between barriers of q).
// Block tile: 128 oc x 32 px; wave w -> oc w*32 (2 m-tiles x 2 n-tiles).
// ---------------------------------------------------------------------------
__global__ __launch_bounds__(256) void dcn_mfma_kernel(
    const float* __restrict__ inp, const float* __restrict__ offm,
    const unsigned short* __restrict__ w_swz, const float* __restrict__ b_dc,
    float* __restrict__ out)
{
    const int tid = threadIdx.x;
    const int bx = blockIdx.x;
    const int lidx = ((bx & 7) << 8) | (bx >> 3);   // XCD swizzle, 2048 blocks
    const int b   = lidx >> 9;
    const int h   = (lidx & 511) >> 2;
    const int pw0 = (lidx & 3) << 5;

    __shared__ int2   s_midx[288];        // [tap][pix]: top/bot pair base idx
    __shared__ float4 s_mwgt[288];        // pair weights (x-validity folded)
    __shared__ unsigned short s_V[32 * 40];

    // ---- bilinear pair metadata: 9 taps x 32 px ----
    for (int i = tid; i < 288; i += 256) {
        int k = i >> 5, p = i & 31;
        int ky = k / 3, kx = k - ky * 3;
        int pw = pw0 + p;
        const float* ob = offm + (size_t)b * 27 * HW_ + h * W_ + pw;
        float offy = ob[(2 * k    ) * HW_];
        float offx = ob[(2 * k + 1) * HW_];
        float mask = ob[(18 + k   ) * HW_];
        float py = offy + (float)(h  + ky - 1);
        float px = offx + (float)(pw + kx - 1);
        float y0f = floorf(py), x0f = floorf(px);
        float ly = py - y0f, lx = px - x0f;
        int y0 = (int)y0f, x0 = (int)x0f;
        int y1 = y0 + 1;
        // x pair: elements [hx, hx+1], validity folded into wlo/whi
        int hx = min(max(x0, 0), W_ - 2);
        float wlo = 0.f, whi = 0.f;
        if (x0 == hx)          { wlo = 1.f - lx; whi = lx; }     // normal
        else if (x0 == hx - 1) { wlo = lx; }                     // x0 == -1
        else if (x0 == hx + 1) { whi = 1.f - lx; }               // x0 == W-1
        float wt_top = ((unsigned)y0 < (unsigned)H_) ? (1.f - ly) * mask : 0.f;
        float wt_bot = ((unsigned)y1 < (unsigned)H_) ? ly * mask : 0.f;
        int cy0 = min(max(y0, 0), H_ - 1), cy1 = min(max(y1, 0), H_ - 1);
        s_midx[i] = make_int2(cy0 * W_ + hx, cy1 * W_ + hx);
        s_mwgt[i] = make_float4(wt_top * wlo, wt_top * whi,
                                wt_bot * wlo, wt_bot * whi);
    }

    const int lane = tid & 63;
    const int wave = tid >> 6;
    const int kg = lane >> 4, pn = lane & 15;
    const int p   = tid & 31;             // build pixel
    const int cg4 = (tid >> 5) << 2;      // build channel base (0,4,...,28)

    const float* gbase = inp + (size_t)b * CIN_ * HW_;

    f32x4 acc[2][2];
#pragma unroll
    for (int mt = 0; mt < 2; ++mt)
#pragma unroll
        for (int nt = 0; nt < 2; ++nt) acc[mt][nt] = (f32x4){0.f, 0.f, 0.f, 0.f};

    f2v pf[8];   // [2j] = top pair, [2j+1] = bot pair, channel cg4+j

    auto issue = [&](int qq, f2v* pfr) {
        int cbq = qq / 9;
        int k   = qq - cbq * 9;
        int2 id = s_midx[(k << 5) + p];
        const float* g = gbase + (size_t)((cbq << 5) + cg4) * HW_;
#pragma unroll
        for (int j = 0; j < 4; ++j) {
            pfr[2 * j]     = *(const f2v*)(g + (size_t)j * HW_ + id.x);
            pfr[2 * j + 1] = *(const f2v*)(g + (size_t)j * HW_ + id.y);
        }
    };

    __syncthreads();   // metadata visible
    issue(0, pf);

    for (int q = 0; q < 36; ++q) {
        int cbq = q / 9;
        int k   = q - cbq * 9;

        // consume prefetched pairs
        float4 wt = s_mwgt[(k << 5) + p];
        float v[4];
#pragma unroll
        for (int j = 0; j < 4; ++j)
            v[j] = pf[2 * j].x * wt.x + pf[2 * j].y * wt.y
                 + pf[2 * j + 1].x * wt.z + pf[2 * j + 1].y * wt.w;
        unsigned r0 = f2bf(v[0]) | (f2bf(v[1]) << 16);
        unsigned r1 = f2bf(v[2]) | (f2bf(v[3]) << 16);

        // A-fragments (L2-hot)
        const short8* wp = (const short8*)w_swz + (size_t)(q * 8 + wave * 2) * 64 + lane;
        short8 af0 = wp[0];
        short8 af1 = wp[64];

        if (q) __syncthreads();           // prior chunk's B reads done
        *(int2*)&s_V[p * 40 + cg4] = make_int2(r0, r1);

        int qn = (q + 1 < 36) ? q + 1 : 35;
        issue(qn, pf);                    // register loads cross the barrier

        __syncthreads();

        short8 bf0 = *(const short8*)&s_V[(pn     ) * 40 + kg * 8];
        short8 bf1 = *(const short8*)&s_V[(16 + pn) * 40 + kg * 8];

        acc[0][0] = __builtin_amdgcn_mfma_f32_16x16x32_bf16(af0, bf0, acc[0][0], 0, 0, 0);
        acc[0][1] = __builtin_amdgcn_mfma_f32_16x16x32_bf16(af0, bf1, acc[0][1], 0, 0, 0);
        acc[1][0] = __builtin_amdgcn_mfma_f32_16x16x32_bf16(af1, bf0, acc[1][0], 0, 0, 0);
        acc[1][1] = __builtin_amdgcn_mfma_f32_16x16x32_bf16(af1, bf1, acc[1][1], 0, 0, 0);
    }

    const int row0 = (lane >> 4) << 2;
    const int col  = lane & 15;
#pragma unroll
    for (int mt = 0; mt < 2; ++mt) {
#pragma unroll
        for (int nt = 0; nt < 2; ++nt) {
            int pw = pw0 + nt * 16 + col;
#pragma unroll
            for (int i = 0; i < 4; ++i) {
                int oc = wave * 32 + mt * 16 + row0 + i;
                out[((size_t)(b * COUT_ + oc)) * HW_ + h * W_ + pw] =
                    acc[mt][nt][i] + b_dc[oc];
            }
        }
    }
}

extern "C" void kernel_launch(void* const* d_in, const int* in_sizes, int n_in,
                              void* d_out, int out_size, void* d_ws, size_t ws_size,
                              hipStream_t stream)
{
    const float* inp   = (const float*)d_in[0];
    const float* feat  = (const float*)d_in[1];
    const float* w_off = (const float*)d_in[2];
    const float* b_off = (const float*)d_in[3];
    const float* w_dc  = (const float*)d_in[4];
    const float* b_dc  = (const float*)d_in[5];
    float* out  = (float*)d_out;
    float* offm = (float*)d_ws;                                            // 7.08 MB
    unsigned short* w_swz    = (unsigned short*)((char*)d_ws + 7077888);           // 288 KB
    unsigned short* woff_swz = (unsigned short*)((char*)d_ws + 7077888 + 294912);  // 72 KB

    woffswz_kernel<<<dim3(18), dim3(256), 0, stream>>>(w_off, woff_swz);
    wswz_kernel<<<dim3(72), dim3(256), 0, stream>>>(w_dc, w_swz);
    offset_mfma_kernel<<<dim3(1024), dim3(256), 0, stream>>>(feat, woff_swz, b_off, offm);
    dcn_mfma_kernel<<<dim3(2048), dim3(256), 0, stream>>>(inp, offm, w_swz, b_dc, out);
}